// Round 1
// baseline (161.185 us; speedup 1.0000x reference)
//
#include <hip/hip_runtime.h>

// RegionSelection: bilinear 2x upsample of attention map (8,1,80,80)->(8,1,160,160),
// per-batch rank-1921 threshold (k=int(0.3*6400)=1920, threshold=topk[k]),
// mask = up >= thr, weighted = local_feat*(mask+0.1).
// Outputs concatenated: weighted (8*256*160*160 fp32) then mask (8*160*160 fp32).

#define NIN   6400    // 80*80
#define NUP   25600   // 160*160
#define KRANK 1921u   // (k+1)-th largest == topv[:, k]

__global__ __launch_bounds__(1024) void upsample_select_kernel(
    const float* __restrict__ att, float* __restrict__ mask_out)
{
    __shared__ float    s_in[NIN];
    __shared__ unsigned s_hist[256];
    __shared__ unsigned s_sel[2];

    const int b   = blockIdx.x;
    const int tid = threadIdx.x;

    // stage 80x80 input tile in LDS (coalesced)
    const float* in = att + b * NIN;
    for (int i = tid; i < NIN; i += 1024) s_in[i] = in[i];
    __syncthreads();

    // each thread computes 25 upsampled values into registers.
    // half-pixel centers: pos = 0.5*i - 0.25; weights are exactly {0.75,0.25};
    // edges (i=0,159) renormalize to weight 1.0 on the boundary pixel.
    float vals[25];
    #pragma unroll
    for (int j = 0; j < 25; ++j) {
        int i = tid + j * 1024;
        int r = i / 160;
        int c = i - r * 160;
        int y0, y1; float wy;
        if (r == 0)        { y0 = 0;  y1 = 0;  wy = 0.0f; }
        else if (r == 159) { y0 = 79; y1 = 79; wy = 0.0f; }
        else { float y = 0.5f * (float)r - 0.25f; y0 = (int)y; y1 = y0 + 1; wy = y - (float)y0; }
        int x0, x1; float wx;
        if (c == 0)        { x0 = 0;  x1 = 0;  wx = 0.0f; }
        else if (c == 159) { x0 = 79; x1 = 79; wx = 0.0f; }
        else { float x = 0.5f * (float)c - 0.25f; x0 = (int)x; x1 = x0 + 1; wx = x - (float)x0; }
        float top = s_in[y0 * 80 + x0] * (1.0f - wx) + s_in[y0 * 80 + x1] * wx;
        float bot = s_in[y1 * 80 + x0] * (1.0f - wx) + s_in[y1 * 80 + x1] * wx;
        vals[j] = top * (1.0f - wy) + bot * wy;
    }

    // exact radix select (MSB->LSB, 8-bit digits) for the KRANK-th largest value.
    // all values are non-negative floats -> uint bit pattern ordering == float ordering.
    unsigned prefix    = 0u;
    unsigned remaining = KRANK;
    for (int shift = 24; shift >= 0; shift -= 8) {
        if (tid < 256) s_hist[tid] = 0u;
        __syncthreads();
        const unsigned pmask = (shift == 24) ? 0u : (0xFFFFFFFFu << (shift + 8));
        #pragma unroll
        for (int j = 0; j < 25; ++j) {
            unsigned v = __float_as_uint(vals[j]);
            if ((v & pmask) == prefix)
                atomicAdd(&s_hist[(v >> shift) & 255u], 1u);
        }
        __syncthreads();
        if (tid == 0) {
            unsigned rem = remaining;
            unsigned dig = 0u;
            for (int d = 255; d >= 0; --d) {
                unsigned cnt = s_hist[d];
                if (cnt >= rem) { dig = (unsigned)d; break; }
                rem -= cnt;
            }
            s_sel[0] = dig;
            s_sel[1] = rem;
        }
        __syncthreads();
        prefix   |= s_sel[0] << shift;
        remaining = s_sel[1];
        __syncthreads();
    }
    const float thr = __uint_as_float(prefix);

    // write mask (same values, same >= comparison as reference -> identical set)
    float* mptr = mask_out + b * NUP;
    #pragma unroll
    for (int j = 0; j < 25; ++j) {
        int i = tid + j * 1024;
        mptr[i] = (vals[j] >= thr) ? 1.0f : 0.0f;
    }
}

// weighted = local_feat * (mask + 0.1), float4-vectorized grid-stride.
// mask is 800 KB total, 256x reuse across channels -> L2-resident.
__global__ __launch_bounds__(256) void apply_mask_kernel(
    const float4* __restrict__ feat, const float4* __restrict__ mask,
    float4* __restrict__ out, int total4)
{
    const int stride = gridDim.x * 256;
    for (int i = blockIdx.x * 256 + threadIdx.x; i < total4; i += stride) {
        int bc  = i / 6400;          // b*256 + c   (6400 = 25600/4 float4 per plane)
        int hw4 = i - bc * 6400;
        int b   = bc >> 8;
        float4 f = feat[i];
        float4 m = mask[b * 6400 + hw4];
        float4 o;
        o.x = f.x * (m.x + 0.1f);
        o.y = f.y * (m.y + 0.1f);
        o.z = f.z * (m.z + 0.1f);
        o.w = f.w * (m.w + 0.1f);
        out[i] = o;
    }
}

extern "C" void kernel_launch(void* const* d_in, const int* in_sizes, int n_in,
                              void* d_out, int out_size, void* d_ws, size_t ws_size,
                              hipStream_t stream)
{
    const float* local_feat = (const float*)d_in[0];   // (8,256,160,160) fp32
    const float* att        = (const float*)d_in[1];   // (8,1,80,80) fp32
    // d_in[2] = spatial_scale (==2, fixed by problem shapes)

    float* out      = (float*)d_out;
    float* mask_out = out + 8 * 256 * 160 * 160;       // second output region

    upsample_select_kernel<<<8, 1024, 0, stream>>>(att, mask_out);

    const int total4 = (8 * 256 * 160 * 160) / 4;      // 13,107,200 float4
    apply_mask_kernel<<<6400, 256, 0, stream>>>(
        (const float4*)local_feat, (const float4*)mask_out, (float4*)out, total4);
}

// Round 3
// 105.287 us; speedup vs baseline: 1.5309x; 1.5309x over previous
//
#include <hip/hip_runtime.h>

// RegionSelection: bilinear 2x upsample of attention map (8,1,80,80)->(8,1,160,160),
// per-batch rank-1921 threshold (k=int(0.3*6400)=1920, threshold=topv[:,k]),
// mask = up >= thr, weighted = local_feat*(mask+0.1).
// Outputs concatenated: weighted (8*256*160*160 fp32) then mask (8*160*160 fp32).

#define NIN   6400    // 80*80
#define NUP   25600   // 160*160
#define KRANK 1921u   // (k+1)-th largest == topv[:, k]

typedef float f32x4 __attribute__((ext_vector_type(4)));

// Wave-parallel "find bin containing rank `rem` counting from the top" over NBINS
// histogram bins. Writes {bin, remaining-within-bin} to s_bcast. Exact.
template <int NBINS>
__device__ inline void find_bin(const unsigned* s_hist, unsigned rem_in,
                                unsigned* s_bcast, int tid)
{
    constexpr int CHUNK = NBINS / 64;
    if (tid < 64) {
        const int lane = tid;
        unsigned csum = 0;
        #pragma unroll
        for (int k = 0; k < CHUNK; ++k) csum += s_hist[lane * CHUNK + k];
        // inclusive suffix sum across lanes: suff[l] = sum csum[l..63]
        unsigned suff = csum;
        #pragma unroll
        for (int off = 1; off < 64; off <<= 1) {
            unsigned o = __shfl_down(suff, off);
            if (lane + off < 64) suff += o;
        }
        unsigned suff_next = __shfl_down(suff, 1);
        if (lane == 63) suff_next = 0;
        if (suff >= rem_in && suff_next < rem_in) {   // exactly one lane
            unsigned r = rem_in - suff_next;          // rank within this chunk (from top)
            int d = lane * CHUNK + CHUNK - 1;
            for (;; --d) {
                unsigned c = s_hist[d];
                if (c >= r) break;
                r -= c;
            }
            s_bcast[0] = (unsigned)d;
            s_bcast[1] = r;
        }
    }
}

__global__ __launch_bounds__(1024) void upsample_select_kernel(
    const float* __restrict__ att, float* __restrict__ mask_out)
{
    __shared__ float    s_in[NIN];
    __shared__ unsigned s_hist[2048];
    __shared__ unsigned s_bcast[2];

    const int b   = blockIdx.x;
    const int tid = threadIdx.x;

    const float* in = att + b * NIN;
    for (int i = tid; i < NIN; i += 1024) s_in[i] = in[i];
    __syncthreads();

    // bilinear 2x upsample, half-pixel centers; weights exactly {0.75,0.25};
    // boundary rows/cols clamp to the edge pixel. (identical to the round-1
    // arithmetic that validated absmax==0)
    unsigned ub[25];
    #pragma unroll
    for (int j = 0; j < 25; ++j) {
        int i = j * 1024 + tid;
        int r = i / 160;
        int c = i - r * 160;
        int y0, y1; float wy;
        if (r == 0)        { y0 = 0;  y1 = 0;  wy = 0.0f; }
        else if (r == 159) { y0 = 79; y1 = 79; wy = 0.0f; }
        else { float y = 0.5f * (float)r - 0.25f; y0 = (int)y; y1 = y0 + 1; wy = y - (float)y0; }
        int x0, x1; float wx;
        if (c == 0)        { x0 = 0;  x1 = 0;  wx = 0.0f; }
        else if (c == 159) { x0 = 79; x1 = 79; wx = 0.0f; }
        else { float x = 0.5f * (float)c - 0.25f; x0 = (int)x; x1 = x0 + 1; wx = x - (float)x0; }
        float top = s_in[y0 * 80 + x0] * (1.0f - wx) + s_in[y0 * 80 + x1] * wx;
        float bot = s_in[y1 * 80 + x0] * (1.0f - wx) + s_in[y1 * 80 + x1] * wx;
        float v   = top * (1.0f - wy) + bot * wy;
        ub[j] = __float_as_uint(v);   // v in [0,1) -> uint order == float order
    }

    // ---- exact radix select, 3 passes: bits [30:20], [19:10], [9:0] ----
    // Pass 1: 2048 bins (wide first digit spreads the hot exponent region
    // across many bins/banks -> no same-address atomic pileup).
    for (int i = tid; i < 2048; i += 1024) s_hist[i] = 0;
    __syncthreads();
    #pragma unroll
    for (int j = 0; j < 25; ++j) atomicAdd(&s_hist[ub[j] >> 20], 1u);  // <0x3F8 < 2048
    __syncthreads();
    find_bin<2048>(s_hist, KRANK, s_bcast, tid);
    __syncthreads();
    const unsigned p1   = s_bcast[0];
    unsigned       rem  = s_bcast[1];
    __syncthreads();

    // Pass 2: among values with bits[30:20]==p1, bin by bits[19:10]
    for (int i = tid; i < 1024; i += 1024) s_hist[i] = 0;
    __syncthreads();
    #pragma unroll
    for (int j = 0; j < 25; ++j) {
        unsigned u = ub[j];
        if ((u >> 20) == p1) atomicAdd(&s_hist[(u >> 10) & 1023u], 1u);
    }
    __syncthreads();
    find_bin<1024>(s_hist, rem, s_bcast, tid);
    __syncthreads();
    const unsigned pref2 = (p1 << 10) | s_bcast[0];
    rem = s_bcast[1];
    __syncthreads();

    // Pass 3: among values with bits[30:10]==pref2, bin by bits[9:0] (exact)
    for (int i = tid; i < 1024; i += 1024) s_hist[i] = 0;
    __syncthreads();
    #pragma unroll
    for (int j = 0; j < 25; ++j) {
        unsigned u = ub[j];
        if ((u >> 10) == pref2) atomicAdd(&s_hist[u & 1023u], 1u);
    }
    __syncthreads();
    find_bin<1024>(s_hist, rem, s_bcast, tid);
    __syncthreads();
    const unsigned thr_bits = (pref2 << 10) | s_bcast[0];

    // mask: same values, same >= comparison as reference -> identical set
    float* mptr = mask_out + b * NUP;
    #pragma unroll
    for (int j = 0; j < 25; ++j)
        mptr[j * 1024 + tid] = (ub[j] >= thr_bits) ? 1.0f : 0.0f;
}

// weighted = local_feat * (mask + 0.1).
// One mask load per thread, then stream CH channels (stride 6400 f32x4).
// Nontemporal on the streaming data so L2 keeps the mask resident.
#define CH 32
__global__ __launch_bounds__(256) void apply_mask_kernel(
    const f32x4* __restrict__ feat, const f32x4* __restrict__ mask,
    f32x4* __restrict__ out)
{
    const int hw4 = blockIdx.x * 256 + threadIdx.x;   // 0..6399 within plane
    const int b   = blockIdx.y;
    const int c0  = blockIdx.z * CH;

    f32x4 m = mask[b * 6400 + hw4];
    f32x4 w = m + 0.1f;

    const int base = (b * 256 + c0) * 6400 + hw4;
    const f32x4* fp = feat + base;
    f32x4*       op = out  + base;

    #pragma unroll 8
    for (int c = 0; c < CH; ++c) {
        f32x4 v = __builtin_nontemporal_load(fp + c * 6400);
        v *= w;
        __builtin_nontemporal_store(v, op + c * 6400);
    }
}

extern "C" void kernel_launch(void* const* d_in, const int* in_sizes, int n_in,
                              void* d_out, int out_size, void* d_ws, size_t ws_size,
                              hipStream_t stream)
{
    const float* local_feat = (const float*)d_in[0];   // (8,256,160,160) fp32
    const float* att        = (const float*)d_in[1];   // (8,1,80,80) fp32
    // d_in[2] = spatial_scale (==2, fixed by problem shapes)

    float* out      = (float*)d_out;
    float* mask_out = out + 8 * 256 * 160 * 160;       // second output region

    upsample_select_kernel<<<8, 1024, 0, stream>>>(att, mask_out);

    dim3 grid(25, 8, 256 / CH);
    apply_mask_kernel<<<grid, 256, 0, stream>>>(
        (const float*)local_feat ? (const f32x4*)local_feat : nullptr,
        (const f32x4*)mask_out, (f32x4*)out);
}